// Round 4
// baseline (13264.919 us; speedup 1.0000x reference)
//
#include <hip/hip_runtime.h>
#include <hip/hip_cooperative_groups.h>
#include <math.h>

namespace cg = cooperative_groups;

#define DC 8220      // dist row stride (28 + 8192)
#define OFF 28
#define NR 4096      // rows of M
#define NC 8192      // cols of M
#define INV4096 (1.0f / 4096.0f)
#define INV8192 (1.0f / 8192.0f)
#define BLK 256

__device__ __forceinline__ float bflo(unsigned int u) { return __uint_as_float(u << 16); }
__device__ __forceinline__ float bfhi(unsigned int u) { return __uint_as_float(u & 0xffff0000u); }
__device__ __forceinline__ unsigned short f2bf(float f) {
    unsigned int i = __float_as_uint(f);
    return (unsigned short)((i + 0x7fffu + ((i >> 16) & 1u)) >> 16);   // RNE
}

// ---- shared device bodies (used by both cooperative and fallback paths) ----

// rowdot over a W-wide bf16 row with fp32 weight vector; lane-0 holds result
template <int W>
__device__ __forceinline__ float rowdot(const unsigned short* __restrict__ row,
                                        const float* __restrict__ w, int lane) {
    float acc = 0.0f;
#pragma unroll
    for (int s = 0; s < W; s += 512) {
        int j = s + lane * 8;
        uint4 a = *(const uint4*)(row + j);
        float4 w0 = *(const float4*)(w + j);
        float4 w1 = *(const float4*)(w + j + 4);
        acc = fmaf(bflo(a.x), w0.x, acc);
        acc = fmaf(bfhi(a.x), w0.y, acc);
        acc = fmaf(bflo(a.y), w0.z, acc);
        acc = fmaf(bfhi(a.y), w0.w, acc);
        acc = fmaf(bflo(a.z), w1.x, acc);
        acc = fmaf(bfhi(a.z), w1.y, acc);
        acc = fmaf(bflo(a.w), w1.z, acc);
        acc = fmaf(bfhi(a.w), w1.w, acc);
    }
#pragma unroll
    for (int o = 32; o; o >>= 1) acc += __shfl_down(acc, o);
    return acc;
}

__device__ __forceinline__ void init_body(const float* __restrict__ dist,
                                          float* __restrict__ rm1, int* __restrict__ arg1,
                                          float* __restrict__ d12, float* __restrict__ wrow,
                                          float* __restrict__ out, int t) {
    if (t == 0) out[0] = 0.0f;
    if (t < NR) {
        float a = dist[(size_t)t * DC + OFF + t];
        float b = dist[(size_t)t * DC + OFF + 4096 + t];
        rm1[t] = fmaxf(a, b);
        arg1[t] = (a >= b) ? t : t + 4096;     // jnp.argmax: first max wins
        wrow[t] = INV4096;                      // u0 = 1/4096
    }
    d12[t] = dist[(size_t)(t & 4095) * DC + OFF + t];
}

__device__ __forceinline__ void build1_chunk(const float* __restrict__ dist,
                                             const float* __restrict__ rm1,
                                             unsigned short* __restrict__ M, int c) {
    int i = c >> 10;
    int j = (c & 1023) << 3;
    float rm = rm1[i];
    const float* Dr = dist + (size_t)i * DC + OFF + j;
    float4 d0 = *(const float4*)Dr;
    float4 d1 = *(const float4*)(Dr + 4);
    float dv[8] = {d0.x, d0.y, d0.z, d0.w, d1.x, d1.y, d1.z, d1.w};
    unsigned short e[8];
#pragma unroll
    for (int k = 0; k < 8; ++k) {
        int jj = j + k;
        bool diag = (jj == i) || (jj == i + 4096);
        float gm = diag ? 0.0f : fmaxf(0.05f + dv[k] - rm, 0.0f);
        e[k] = f2bf(__expf(5.0f * __expf(-gm)));
    }
    uint4 o;
    o.x = (unsigned int)e[0] | ((unsigned int)e[1] << 16);
    o.y = (unsigned int)e[2] | ((unsigned int)e[3] << 16);
    o.z = (unsigned int)e[4] | ((unsigned int)e[5] << 16);
    o.w = (unsigned int)e[6] | ((unsigned int)e[7] << 16);
    *(uint4*)(M + (size_t)c * 8) = o;
}

__device__ __forceinline__ void build2_chunk(const float* __restrict__ dist,
                                             const float* __restrict__ d12,
                                             unsigned short* __restrict__ M, int c) {
    int r = c >> 10;
    int col = (c & 1023) << 3;
    const float* Dr = dist + (size_t)r * DC + OFF + col;
    float4 d0 = *(const float4*)Dr;
    float4 d1 = *(const float4*)(Dr + 4);
    float4 e0 = *(const float4*)(d12 + col);
    float4 e1 = *(const float4*)(d12 + col + 4);
    float dv[8] = {d0.x, d0.y, d0.z, d0.w, d1.x, d1.y, d1.z, d1.w};
    float dd[8] = {e0.x, e0.y, e0.z, e0.w, e1.x, e1.y, e1.z, e1.w};
    unsigned short e[8];
#pragma unroll
    for (int k = 0; k < 8; ++k) {
        int cc = col + k;
        bool diag = (r == (cc & 4095));
        float gm = diag ? 0.0f : fmaxf(0.05f + dv[k] - dd[k], 0.0f);
        e[k] = f2bf(__expf(5.0f * __expf(-gm)));
    }
    uint4 o;
    o.x = (unsigned int)e[0] | ((unsigned int)e[1] << 16);
    o.y = (unsigned int)e[2] | ((unsigned int)e[3] << 16);
    o.z = (unsigned int)e[4] | ((unsigned int)e[5] << 16);
    o.w = (unsigned int)e[6] | ((unsigned int)e[7] << 16);
    *(uint4*)(M + (size_t)c * 8) = o;
}

// one 64x64 bf16 tile transpose: M (4096x8192) -> MT (8192x4096); t in [0,8192)
__device__ __forceinline__ void tile_transpose(const unsigned short* __restrict__ M,
                                               unsigned short* __restrict__ MT,
                                               unsigned int (*tile)[33], int t, int tid) {
    int r0 = (t >> 7) * 64;
    int c0 = (t & 127) * 64;
    int lc = tid & 7, rr = tid >> 3;
#pragma unroll
    for (int s = 0; s < 2; ++s) {
        int r = rr + s * 32;
        uint4 a = *(const uint4*)(M + (size_t)(r0 + r) * NC + c0 + lc * 8);
        tile[r][lc * 4 + 0] = a.x;
        tile[r][lc * 4 + 1] = a.y;
        tile[r][lc * 4 + 2] = a.z;
        tile[r][lc * 4 + 3] = a.w;
    }
    __syncthreads();
    int cc = tid >> 2, rs = (tid & 3) * 16;
    unsigned int o[8];
#pragma unroll
    for (int w = 0; w < 8; ++w) {
        unsigned int ue = tile[rs + 2 * w][cc >> 1];
        unsigned int uo = tile[rs + 2 * w + 1][cc >> 1];
        unsigned short e = (cc & 1) ? (unsigned short)(ue >> 16) : (unsigned short)(ue & 0xffffu);
        unsigned short d = (cc & 1) ? (unsigned short)(uo >> 16) : (unsigned short)(uo & 0xffffu);
        o[w] = (unsigned int)e | ((unsigned int)d << 16);
    }
    unsigned short* dst = MT + (size_t)(c0 + cc) * NR + r0 + rs;
    *(uint4*)dst = make_uint4(o[0], o[1], o[2], o[3]);
    *(uint4*)(dst + 8) = make_uint4(o[4], o[5], o[6], o[7]);
    __syncthreads();
}

__device__ __forceinline__ void epi1_row(const unsigned short* __restrict__ M,
                                         const float* __restrict__ dist,
                                         const float* __restrict__ wcol,
                                         const float* __restrict__ rm1,
                                         const int* __restrict__ arg1,
                                         float* __restrict__ out, int i, int lane) {
    float rm = rm1[i];
    int arg = arg1[i];
    const unsigned short* Ar = M + (size_t)i * NC;
    const float* Dr = dist + (size_t)i * DC + OFF;
    float num = 0.0f, den = 0.0f;
#pragma unroll
    for (int s = 0; s < NC; s += 512) {
        int j0 = s + lane * 8;
        uint4 a = *(const uint4*)(Ar + j0);
        float4 t0 = *(const float4*)(wcol + j0);
        float4 t1 = *(const float4*)(wcol + j0 + 4);
        float4 d0 = *(const float4*)(Dr + j0);
        float4 d1 = *(const float4*)(Dr + j0 + 4);
        float av[8] = {bflo(a.x), bfhi(a.x), bflo(a.y), bfhi(a.y),
                       bflo(a.z), bfhi(a.z), bflo(a.w), bfhi(a.w)};
        float tv[8] = {t0.x, t0.y, t0.z, t0.w, t1.x, t1.y, t1.z, t1.w};
        float dv[8] = {d0.x, d0.y, d0.z, d0.w, d1.x, d1.y, d1.z, d1.w};
#pragma unroll
        for (int e = 0; e < 8; ++e) {
            int jj = j0 + e;
            bool isdiag = (jj == i) || (jj == i + 4096);
            float gm = isdiag ? fmaxf(rm - 0.5f - dv[e], 0.0f)
                              : fmaxf(0.05f + dv[e] - rm, 0.0f);
            bool keep = (jj != arg) && ((jj < 4096) || (jj == i + 4096));
            float wv = keep ? av[e] * tv[e] : 0.0f;
            num += wv * gm;
            den += wv;
        }
    }
#pragma unroll
    for (int o = 32; o; o >>= 1) {
        num += __shfl_down(num, o);
        den += __shfl_down(den, o);
    }
    if (lane == 0) atomicAdd(out, num / den);
}

__device__ __forceinline__ void epi2_body(const unsigned short* __restrict__ M,
                                          const float* __restrict__ dist,
                                          const float* __restrict__ wrow,
                                          const float* __restrict__ d12,
                                          float* __restrict__ numb, float* __restrict__ denb,
                                          float* wsm, int t, int tid) {
    int r0 = (t >> 3) * 64;
    int c = (t & 7) * 1024 + tid * 4;
    if (tid < 64) wsm[tid] = wrow[r0 + tid];
    __syncthreads();
    float4 e0 = *(const float4*)(d12 + c);
    float dd[4] = {e0.x, e0.y, e0.z, e0.w};
    float nacc[4] = {0.f, 0.f, 0.f, 0.f};
    float dacc[4] = {0.f, 0.f, 0.f, 0.f};
    for (int r = 0; r < 64; ++r) {
        int rr = r0 + r;
        uint2 a = *(const uint2*)(M + (size_t)rr * NC + c);
        float4 dv4 = *(const float4*)(dist + (size_t)rr * DC + OFF + c);
        float av[4] = {bflo(a.x), bfhi(a.x), bflo(a.y), bfhi(a.y)};
        float dv[4] = {dv4.x, dv4.y, dv4.z, dv4.w};
        float ww = wsm[r];
#pragma unroll
        for (int e = 0; e < 4; ++e) {
            int cc = c + e;
            bool isdiag = (rr == (cc & 4095));
            float gm = fmaxf(0.05f + dv[e] - dd[e], 0.0f);
            float wv = isdiag ? 0.0f : av[e] * ww;
            nacc[e] += wv * gm;
            dacc[e] += wv;
        }
    }
#pragma unroll
    for (int e = 0; e < 4; ++e) {
        atomicAdd(&numb[c + e], nacc[e]);
        atomicAdd(&denb[c + e], dacc[e]);
    }
    __syncthreads();
}

// ------------------------- cooperative persistent kernel -------------------
__global__ __launch_bounds__(BLK, 4) void k_main(const float* __restrict__ dist,
                                                 float* __restrict__ out,
                                                 unsigned short* __restrict__ M,
                                                 unsigned short* __restrict__ MT,
                                                 float* __restrict__ wrow,
                                                 float* __restrict__ wcol,
                                                 float* __restrict__ rm1,
                                                 int* __restrict__ arg1,
                                                 float* __restrict__ d12,
                                                 float* __restrict__ numb,
                                                 float* __restrict__ denb) {
    cg::grid_group grid = cg::this_grid();
    const int tid = threadIdx.x, bid = blockIdx.x;
    const int nb = gridDim.x, nt = nb * BLK;
    const int gt = bid * BLK + tid;
    const int nw = nt >> 6, wave = gt >> 6, lane = tid & 63;
    __shared__ unsigned int tile[64][33];
    __shared__ float wsm[64];

    for (int t = gt; t < NC; t += nt) init_body(dist, rm1, arg1, d12, wrow, out, t);
    grid.sync();
    for (int c = gt; c < NR * NC / 8; c += nt) build1_chunk(dist, rm1, M, c);
    grid.sync();
    for (int t = bid; t < 8192; t += nb) tile_transpose(M, MT, tile, t, tid);
    grid.sync();

    for (int it = 0; it < 50; ++it) {
        for (int r = wave; r < NC; r += nw) {
            float s = rowdot<NR>(MT + (size_t)r * NR, wrow, lane);
            if (lane == 0) wcol[r] = __fdividef(INV8192, s);
        }
        grid.sync();
        if (it == 49) break;                    // last wrow update is dead
        for (int r = wave; r < NR; r += nw) {
            float s = rowdot<NC>(M + (size_t)r * NC, wcol, lane);
            if (lane == 0) wrow[r] = __fdividef(INV4096, s);
        }
        grid.sync();
    }
    for (int i = wave; i < NR; i += nw) epi1_row(M, dist, wcol, rm1, arg1, out, i, lane);
    grid.sync();

    for (int t = gt; t < NC; t += nt) { wcol[t] = INV8192; numb[t] = 0.0f; denb[t] = 0.0f; }
    for (int c = gt; c < NR * NC / 8; c += nt) build2_chunk(dist, d12, M, c);
    grid.sync();
    for (int t = bid; t < 8192; t += nb) tile_transpose(M, MT, tile, t, tid);
    grid.sync();

    for (int it = 0; it < 50; ++it) {
        for (int r = wave; r < NR; r += nw) {
            float s = rowdot<NC>(M + (size_t)r * NC, wcol, lane);
            if (lane == 0) wrow[r] = __fdividef(INV4096, s);
        }
        grid.sync();
        if (it == 49) break;                    // last wcol update is dead
        for (int r = wave; r < NC; r += nw) {
            float s = rowdot<NR>(MT + (size_t)r * NR, wrow, lane);
            if (lane == 0) wcol[r] = __fdividef(INV8192, s);
        }
        grid.sync();
    }
    for (int t = bid; t < 512; t += nb) epi2_body(M, dist, wrow, d12, numb, denb, wsm, t, tid);
    grid.sync();
    for (int t = wave; t < 128; t += nw) {
        int c = t * 64 + lane;
        float v = numb[c] / denb[c];
#pragma unroll
        for (int o = 32; o; o >>= 1) v += __shfl_down(v, o);
        if (lane == 0) atomicAdd(out, v);
    }
}

// ------------------------- fallback multi-kernel path ----------------------
__global__ __launch_bounds__(BLK) void k_fb_init(const float* __restrict__ dist,
                                                 float* __restrict__ rm1, int* __restrict__ arg1,
                                                 float* __restrict__ d12, float* __restrict__ wrow,
                                                 float* __restrict__ out) {
    init_body(dist, rm1, arg1, d12, wrow, out, blockIdx.x * BLK + threadIdx.x);
}
__global__ __launch_bounds__(BLK) void k_fb_build1(const float* __restrict__ dist,
                                                   const float* __restrict__ rm1,
                                                   unsigned short* __restrict__ M) {
    build1_chunk(dist, rm1, M, blockIdx.x * BLK + threadIdx.x);
}
__global__ __launch_bounds__(BLK) void k_fb_build2(const float* __restrict__ dist,
                                                   const float* __restrict__ d12,
                                                   unsigned short* __restrict__ M) {
    build2_chunk(dist, d12, M, blockIdx.x * BLK + threadIdx.x);
}
__global__ __launch_bounds__(BLK) void k_fb_transp(const unsigned short* __restrict__ M,
                                                   unsigned short* __restrict__ MT) {
    __shared__ unsigned int tile[64][33];
    tile_transpose(M, MT, tile, blockIdx.x, threadIdx.x);
}
template <int W>
__global__ __launch_bounds__(BLK) void k_fb_matvec(const unsigned short* __restrict__ Mat,
                                                   const float* __restrict__ w,
                                                   float* __restrict__ outv, float scale) {
    int r = blockIdx.x * 4 + (threadIdx.x >> 6);
    float s = rowdot<W>(Mat + (size_t)r * W, w, threadIdx.x & 63);
    if ((threadIdx.x & 63) == 0) outv[r] = __fdividef(scale, s);
}
__global__ __launch_bounds__(BLK) void k_fb_epi1(const unsigned short* __restrict__ M,
                                                 const float* __restrict__ dist,
                                                 const float* __restrict__ wcol,
                                                 const float* __restrict__ rm1,
                                                 const int* __restrict__ arg1,
                                                 float* __restrict__ out) {
    epi1_row(M, dist, wcol, rm1, arg1, out,
             blockIdx.x * 4 + (threadIdx.x >> 6), threadIdx.x & 63);
}
__global__ __launch_bounds__(BLK) void k_fb_init2(float* __restrict__ wcol,
                                                  float* __restrict__ numb,
                                                  float* __restrict__ denb) {
    int t = blockIdx.x * BLK + threadIdx.x;
    wcol[t] = INV8192;
    numb[t] = 0.0f;
    denb[t] = 0.0f;
}
__global__ __launch_bounds__(BLK) void k_fb_epi2(const unsigned short* __restrict__ M,
                                                 const float* __restrict__ dist,
                                                 const float* __restrict__ wrow,
                                                 const float* __restrict__ d12,
                                                 float* __restrict__ numb,
                                                 float* __restrict__ denb) {
    __shared__ float wsm[64];
    epi2_body(M, dist, wrow, d12, numb, denb, wsm, blockIdx.x, threadIdx.x);
}
__global__ __launch_bounds__(BLK) void k_fb_epi2fin(const float* __restrict__ numb,
                                                    const float* __restrict__ denb,
                                                    float* __restrict__ out) {
    int c = blockIdx.x * BLK + threadIdx.x;
    float v = numb[c] / denb[c];
    __shared__ float sm[4];
#pragma unroll
    for (int o = 32; o; o >>= 1) v += __shfl_down(v, o);
    if ((threadIdx.x & 63) == 0) sm[threadIdx.x >> 6] = v;
    __syncthreads();
    if (threadIdx.x == 0) atomicAdd(out, sm[0] + sm[1] + sm[2] + sm[3]);
}

// ---------------------------------------------------------------------------
extern "C" void kernel_launch(void* const* d_in, const int* in_sizes, int n_in,
                              void* d_out, int out_size, void* d_ws, size_t ws_size,
                              hipStream_t stream) {
    const float* dist = (const float*)d_in[0];
    float* out = (float*)d_out;

    unsigned short* M  = (unsigned short*)d_ws;                 // 64 MB
    unsigned short* MT = M + (size_t)NR * NC;                   // 64 MB
    float* fb   = (float*)(MT + (size_t)NR * NC);
    float* wrow = fb;                 // 4096
    float* wcol = wrow + NR;          // 8192
    float* rm1  = wcol + NC;          // 4096
    int*   arg1 = (int*)(rm1 + NR);   // 4096
    float* d12  = (float*)(arg1 + NR);// 8192
    float* numb = d12 + NC;           // 8192
    float* denb = numb + NC;          // 8192

    // ---- try cooperative persistent kernel with adaptive grid ----
    int dev = 0;
    (void)hipGetDevice(&dev);
    int numCU = 0;
    (void)hipDeviceGetAttribute(&numCU, hipDeviceAttributeMultiprocessorCount, dev);
    int maxPerCU = 0;
    (void)hipOccupancyMaxActiveBlocksPerMultiprocessor(&maxPerCU, (const void*)k_main, BLK, 0);

    hipError_t rc = hipErrorUnknown;
    int grid = (numCU > 0 && maxPerCU > 0) ? maxPerCU * numCU : 0;
    if (grid > 1024) grid = 1024;
    void* args[] = {(void*)&dist, (void*)&out, (void*)&M, (void*)&MT,
                    (void*)&wrow, (void*)&wcol, (void*)&rm1, (void*)&arg1,
                    (void*)&d12, (void*)&numb, (void*)&denb};
    for (int g = grid; g >= 128 && rc != hipSuccess; g >>= 1) {
        rc = hipLaunchCooperativeKernel((void*)k_main, dim3(g), dim3(BLK), args, 0, stream);
        if (rc != hipSuccess) (void)hipGetLastError();   // clear sticky error
    }
    if (rc == hipSuccess) return;

    // ---- fallback: multi-kernel graph path (guaranteed) ----
    k_fb_init<<<32, BLK, 0, stream>>>(dist, rm1, arg1, d12, wrow, out);
    k_fb_build1<<<16384, BLK, 0, stream>>>(dist, rm1, M);
    k_fb_transp<<<8192, BLK, 0, stream>>>(M, MT);
    for (int it = 0; it < 50; ++it) {
        k_fb_matvec<NR><<<2048, BLK, 0, stream>>>(MT, wrow, wcol, INV8192);
        if (it == 49) break;
        k_fb_matvec<NC><<<1024, BLK, 0, stream>>>(M, wcol, wrow, INV4096);
    }
    k_fb_epi1<<<1024, BLK, 0, stream>>>(M, dist, wcol, rm1, arg1, out);

    k_fb_build2<<<16384, BLK, 0, stream>>>(dist, d12, M);
    k_fb_init2<<<32, BLK, 0, stream>>>(wcol, numb, denb);
    k_fb_transp<<<8192, BLK, 0, stream>>>(M, MT);
    for (int it = 0; it < 50; ++it) {
        k_fb_matvec<NC><<<1024, BLK, 0, stream>>>(M, wcol, wrow, INV4096);
        if (it == 49) break;
        k_fb_matvec<NR><<<2048, BLK, 0, stream>>>(MT, wrow, wcol, INV8192);
    }
    k_fb_epi2<<<512, BLK, 0, stream>>>(M, dist, wrow, d12, numb, denb);
    k_fb_epi2fin<<<32, BLK, 0, stream>>>(numb, denb, out);
}

// Round 5
// 6665.523 us; speedup vs baseline: 1.9901x; 1.9901x over previous
//
#include <hip/hip_runtime.h>
#include <hip/hip_cooperative_groups.h>
#include <math.h>

namespace cg = cooperative_groups;

#define DC 8220      // dist row stride (28 + 8192)
#define OFF 28
#define NR 4096      // rows of M
#define NC 8192      // cols of M
#define INV4096 (1.0f / 4096.0f)
#define INV8192 (1.0f / 8192.0f)
#define BLK 256

#define AGENT __HIP_MEMORY_SCOPE_AGENT

__device__ __forceinline__ float bflo(unsigned int u) { return __uint_as_float(u << 16); }
__device__ __forceinline__ float bfhi(unsigned int u) { return __uint_as_float(u & 0xffff0000u); }
__device__ __forceinline__ unsigned short f2bf(float f) {
    unsigned int i = __float_as_uint(f);
    return (unsigned short)((i + 0x7fffu + ((i >> 16) & 1u)) >> 16);   // RNE
}
// LDS bank swizzle on 16B granules: spreads stride-32B lane pattern over all banks
__device__ __forceinline__ int swz(int g) { return g ^ ((g >> 3) & 7); }

// --------------- lightweight grid barrier (no cache flush) -----------------
// All cross-phase data goes through agent-scope atomics (coherence point), so
// the barrier only needs execution ordering + vmcnt drain, not L2 flushes.
__device__ __forceinline__ void gbar(unsigned int* ctr, unsigned int target) {
    __syncthreads();
    if (threadIdx.x == 0) {
        asm volatile("s_waitcnt vmcnt(0)" ::: "memory");  // prior atomic stores done
        __hip_atomic_fetch_add(ctr, 1u, __ATOMIC_RELAXED, AGENT);
        while (__hip_atomic_load(ctr, __ATOMIC_RELAXED, AGENT) < target)
            __builtin_amdgcn_s_sleep(2);
    }
    __syncthreads();
}

// stage n floats of w (atomic, coherent) into swizzled LDS granules
__device__ __forceinline__ void stage_w(const float* __restrict__ w, float4* wl4,
                                        int n, int tid) {
    for (int g = tid; g < (n >> 2); g += BLK) {
        unsigned long long lo = __hip_atomic_load((unsigned long long*)(w + g * 4),
                                                  __ATOMIC_RELAXED, AGENT);
        unsigned long long hi = __hip_atomic_load((unsigned long long*)(w + g * 4 + 2),
                                                  __ATOMIC_RELAXED, AGENT);
        float4 v;
        v.x = __uint_as_float((unsigned int)lo);
        v.y = __uint_as_float((unsigned int)(lo >> 32));
        v.z = __uint_as_float((unsigned int)hi);
        v.w = __uint_as_float((unsigned int)(hi >> 32));
        wl4[swz(g)] = v;
    }
    __syncthreads();
}

// rowdot: one row, w from swizzled LDS
template <int W>
__device__ __forceinline__ float rowdot_lds(const unsigned short* __restrict__ row,
                                            const float4* __restrict__ wl4, int lane) {
    float acc = 0.0f;
#pragma unroll 8
    for (int s = 0; s < W; s += 512) {
        int j = s + lane * 8;
        uint4 a = *(const uint4*)(row + j);
        int g = j >> 2;
        float4 w0 = wl4[swz(g)];
        float4 w1 = wl4[swz(g + 1)];
        acc = fmaf(bflo(a.x), w0.x, acc);
        acc = fmaf(bfhi(a.x), w0.y, acc);
        acc = fmaf(bflo(a.y), w0.z, acc);
        acc = fmaf(bfhi(a.y), w0.w, acc);
        acc = fmaf(bflo(a.z), w1.x, acc);
        acc = fmaf(bfhi(a.z), w1.y, acc);
        acc = fmaf(bflo(a.w), w1.z, acc);
        acc = fmaf(bfhi(a.w), w1.w, acc);
    }
#pragma unroll
    for (int o = 32; o; o >>= 1) acc += __shfl_down(acc, o);
    return acc;
}

// rowdot for two rows sharing one w (phase A: doubles loads in flight)
__device__ __forceinline__ void rowdot2_lds(const unsigned short* __restrict__ r0,
                                            const unsigned short* __restrict__ r1,
                                            const float4* __restrict__ wl4, int lane,
                                            float& o0, float& o1) {
    float a0 = 0.0f, a1 = 0.0f;
#pragma unroll
    for (int s = 0; s < NR; s += 512) {
        int j = s + lane * 8;
        uint4 a = *(const uint4*)(r0 + j);
        uint4 b = *(const uint4*)(r1 + j);
        int g = j >> 2;
        float4 w0 = wl4[swz(g)];
        float4 w1 = wl4[swz(g + 1)];
        a0 = fmaf(bflo(a.x), w0.x, a0); a1 = fmaf(bflo(b.x), w0.x, a1);
        a0 = fmaf(bfhi(a.x), w0.y, a0); a1 = fmaf(bfhi(b.x), w0.y, a1);
        a0 = fmaf(bflo(a.y), w0.z, a0); a1 = fmaf(bflo(b.y), w0.z, a1);
        a0 = fmaf(bfhi(a.y), w0.w, a0); a1 = fmaf(bfhi(b.y), w0.w, a1);
        a0 = fmaf(bflo(a.z), w1.x, a0); a1 = fmaf(bflo(b.z), w1.x, a1);
        a0 = fmaf(bfhi(a.z), w1.y, a0); a1 = fmaf(bfhi(b.z), w1.y, a1);
        a0 = fmaf(bflo(a.w), w1.z, a0); a1 = fmaf(bflo(b.w), w1.z, a1);
        a0 = fmaf(bfhi(a.w), w1.w, a0); a1 = fmaf(bfhi(b.w), w1.w, a1);
    }
#pragma unroll
    for (int o = 32; o; o >>= 1) {
        a0 += __shfl_down(a0, o);
        a1 += __shfl_down(a1, o);
    }
    o0 = a0; o1 = a1;
}

// ---------------- shared phase bodies (also used by fallback) --------------
__device__ __forceinline__ void init_body(const float* __restrict__ dist,
                                          float* __restrict__ rm1, int* __restrict__ arg1,
                                          float* __restrict__ d12, float* __restrict__ wrow,
                                          float* __restrict__ out, int t) {
    if (t == 0) __hip_atomic_store(out, 0.0f, __ATOMIC_RELAXED, AGENT);
    if (t < NR) {
        float a = dist[(size_t)t * DC + OFF + t];
        float b = dist[(size_t)t * DC + OFF + 4096 + t];
        rm1[t] = fmaxf(a, b);
        arg1[t] = (a >= b) ? t : t + 4096;     // jnp.argmax: first max wins
        __hip_atomic_store(&wrow[t], INV4096, __ATOMIC_RELAXED, AGENT);
    }
    d12[t] = dist[(size_t)(t & 4095) * DC + OFF + t];
}

__device__ __forceinline__ void build1_chunk(const float* __restrict__ dist,
                                             const float* __restrict__ rm1,
                                             unsigned short* __restrict__ M, int c) {
    int i = c >> 10;
    int j = (c & 1023) << 3;
    float rm = rm1[i];
    const float* Dr = dist + (size_t)i * DC + OFF + j;
    float4 d0 = *(const float4*)Dr;
    float4 d1 = *(const float4*)(Dr + 4);
    float dv[8] = {d0.x, d0.y, d0.z, d0.w, d1.x, d1.y, d1.z, d1.w};
    unsigned short e[8];
#pragma unroll
    for (int k = 0; k < 8; ++k) {
        int jj = j + k;
        bool diag = (jj == i) || (jj == i + 4096);
        float gm = diag ? 0.0f : fmaxf(0.05f + dv[k] - rm, 0.0f);
        e[k] = f2bf(__expf(5.0f * __expf(-gm)));
    }
    uint4 o;
    o.x = (unsigned int)e[0] | ((unsigned int)e[1] << 16);
    o.y = (unsigned int)e[2] | ((unsigned int)e[3] << 16);
    o.z = (unsigned int)e[4] | ((unsigned int)e[5] << 16);
    o.w = (unsigned int)e[6] | ((unsigned int)e[7] << 16);
    *(uint4*)(M + (size_t)c * 8) = o;
}

__device__ __forceinline__ void build2_chunk(const float* __restrict__ dist,
                                             const float* __restrict__ d12,
                                             unsigned short* __restrict__ M, int c) {
    int r = c >> 10;
    int col = (c & 1023) << 3;
    const float* Dr = dist + (size_t)r * DC + OFF + col;
    float4 d0 = *(const float4*)Dr;
    float4 d1 = *(const float4*)(Dr + 4);
    float4 e0 = *(const float4*)(d12 + col);
    float4 e1 = *(const float4*)(d12 + col + 4);
    float dv[8] = {d0.x, d0.y, d0.z, d0.w, d1.x, d1.y, d1.z, d1.w};
    float dd[8] = {e0.x, e0.y, e0.z, e0.w, e1.x, e1.y, e1.z, e1.w};
    unsigned short e[8];
#pragma unroll
    for (int k = 0; k < 8; ++k) {
        int cc = col + k;
        bool diag = (r == (cc & 4095));
        float gm = diag ? 0.0f : fmaxf(0.05f + dv[k] - dd[k], 0.0f);
        e[k] = f2bf(__expf(5.0f * __expf(-gm)));
    }
    uint4 o;
    o.x = (unsigned int)e[0] | ((unsigned int)e[1] << 16);
    o.y = (unsigned int)e[2] | ((unsigned int)e[3] << 16);
    o.z = (unsigned int)e[4] | ((unsigned int)e[5] << 16);
    o.w = (unsigned int)e[6] | ((unsigned int)e[7] << 16);
    *(uint4*)(M + (size_t)c * 8) = o;
}

__device__ __forceinline__ void tile_transpose(const unsigned short* __restrict__ M,
                                               unsigned short* __restrict__ MT,
                                               unsigned int (*tile)[33], int t, int tid) {
    int r0 = (t >> 7) * 64;
    int c0 = (t & 127) * 64;
    int lc = tid & 7, rr = tid >> 3;
#pragma unroll
    for (int s = 0; s < 2; ++s) {
        int r = rr + s * 32;
        uint4 a = *(const uint4*)(M + (size_t)(r0 + r) * NC + c0 + lc * 8);
        tile[r][lc * 4 + 0] = a.x;
        tile[r][lc * 4 + 1] = a.y;
        tile[r][lc * 4 + 2] = a.z;
        tile[r][lc * 4 + 3] = a.w;
    }
    __syncthreads();
    int cc = tid >> 2, rs = (tid & 3) * 16;
    unsigned int o[8];
#pragma unroll
    for (int w = 0; w < 8; ++w) {
        unsigned int ue = tile[rs + 2 * w][cc >> 1];
        unsigned int uo = tile[rs + 2 * w + 1][cc >> 1];
        unsigned short e = (cc & 1) ? (unsigned short)(ue >> 16) : (unsigned short)(ue & 0xffffu);
        unsigned short d = (cc & 1) ? (unsigned short)(uo >> 16) : (unsigned short)(uo & 0xffffu);
        o[w] = (unsigned int)e | ((unsigned int)d << 16);
    }
    unsigned short* dst = MT + (size_t)(c0 + cc) * NR + r0 + rs;
    *(uint4*)dst = make_uint4(o[0], o[1], o[2], o[3]);
    *(uint4*)(dst + 8) = make_uint4(o[4], o[5], o[6], o[7]);
    __syncthreads();
}

__device__ __forceinline__ void epi1_row_lds(const unsigned short* __restrict__ M,
                                             const float* __restrict__ dist,
                                             const float4* __restrict__ wl4,
                                             const float* __restrict__ rm1,
                                             const int* __restrict__ arg1,
                                             float* __restrict__ out, int i, int lane) {
    float rm = rm1[i];
    int arg = arg1[i];
    const unsigned short* Ar = M + (size_t)i * NC;
    const float* Dr = dist + (size_t)i * DC + OFF;
    float num = 0.0f, den = 0.0f;
#pragma unroll 4
    for (int s = 0; s < NC; s += 512) {
        int j0 = s + lane * 8;
        uint4 a = *(const uint4*)(Ar + j0);
        int g = j0 >> 2;
        float4 t0 = wl4[swz(g)];
        float4 t1 = wl4[swz(g + 1)];
        float4 d0 = *(const float4*)(Dr + j0);
        float4 d1 = *(const float4*)(Dr + j0 + 4);
        float av[8] = {bflo(a.x), bfhi(a.x), bflo(a.y), bfhi(a.y),
                       bflo(a.z), bfhi(a.z), bflo(a.w), bfhi(a.w)};
        float tv[8] = {t0.x, t0.y, t0.z, t0.w, t1.x, t1.y, t1.z, t1.w};
        float dv[8] = {d0.x, d0.y, d0.z, d0.w, d1.x, d1.y, d1.z, d1.w};
#pragma unroll
        for (int e = 0; e < 8; ++e) {
            int jj = j0 + e;
            bool isdiag = (jj == i) || (jj == i + 4096);
            float gm = isdiag ? fmaxf(rm - 0.5f - dv[e], 0.0f)
                              : fmaxf(0.05f + dv[e] - rm, 0.0f);
            bool keep = (jj != arg) && ((jj < 4096) || (jj == i + 4096));
            float wv = keep ? av[e] * tv[e] : 0.0f;
            num += wv * gm;
            den += wv;
        }
    }
#pragma unroll
    for (int o = 32; o; o >>= 1) {
        num += __shfl_down(num, o);
        den += __shfl_down(den, o);
    }
    if (lane == 0) atomicAdd(out, num / den);
}

__device__ __forceinline__ void epi2_body(const unsigned short* __restrict__ M,
                                          const float* __restrict__ dist,
                                          const float* __restrict__ wrow,
                                          const float* __restrict__ d12,
                                          float* __restrict__ numb, float* __restrict__ denb,
                                          float* wsm, int t, int tid, bool coherent_w) {
    int r0 = (t >> 3) * 64;
    int c = (t & 7) * 1024 + tid * 4;
    if (tid < 64) {
        wsm[tid] = coherent_w ? __hip_atomic_load(&wrow[r0 + tid], __ATOMIC_RELAXED, AGENT)
                              : wrow[r0 + tid];
    }
    __syncthreads();
    float4 e0 = *(const float4*)(d12 + c);
    float dd[4] = {e0.x, e0.y, e0.z, e0.w};
    float nacc[4] = {0.f, 0.f, 0.f, 0.f};
    float dacc[4] = {0.f, 0.f, 0.f, 0.f};
    for (int r = 0; r < 64; ++r) {
        int rr = r0 + r;
        uint2 a = *(const uint2*)(M + (size_t)rr * NC + c);
        float4 dv4 = *(const float4*)(dist + (size_t)rr * DC + OFF + c);
        float av[4] = {bflo(a.x), bfhi(a.x), bflo(a.y), bfhi(a.y)};
        float dv[4] = {dv4.x, dv4.y, dv4.z, dv4.w};
        float ww = wsm[r];
#pragma unroll
        for (int e = 0; e < 4; ++e) {
            int cc = c + e;
            bool isdiag = (rr == (cc & 4095));
            float gm = fmaxf(0.05f + dv[e] - dd[e], 0.0f);
            float wv = isdiag ? 0.0f : av[e] * ww;
            nacc[e] += wv * gm;
            dacc[e] += wv;
        }
    }
#pragma unroll
    for (int e = 0; e < 4; ++e) {
        atomicAdd(&numb[c + e], nacc[e]);
        atomicAdd(&denb[c + e], dacc[e]);
    }
    __syncthreads();
}

// ------------------------- cooperative persistent kernel -------------------
__global__ __launch_bounds__(BLK, 4) void k_main(const float* __restrict__ dist,
                                                 float* __restrict__ out,
                                                 unsigned short* __restrict__ M,
                                                 unsigned short* __restrict__ MT,
                                                 float* __restrict__ wrow,
                                                 float* __restrict__ wcol,
                                                 float* __restrict__ rm1,
                                                 int* __restrict__ arg1,
                                                 float* __restrict__ d12,
                                                 float* __restrict__ numb,
                                                 float* __restrict__ denb,
                                                 unsigned int* __restrict__ ctr) {
    cg::grid_group grid = cg::this_grid();
    const int tid = threadIdx.x, bid = blockIdx.x;
    const int nb = gridDim.x, nt = nb * BLK;
    const int gt = bid * BLK + tid;
    const int nw = nt >> 6, wave = gt >> 6, lane = tid & 63;
    unsigned int pc = 0;                       // barrier phase count (per-thread)

    extern __shared__ char smem[];             // 32 KB dynamic
    float4* wl4 = (float4*)smem;
    unsigned int (*tile)[33] = (unsigned int(*)[33])smem;
    float* wsm = (float*)smem;

    for (int t = gt; t < NC; t += nt) init_body(dist, rm1, arg1, d12, wrow, out, t);
    grid.sync();
    for (int c = gt; c < NR * NC / 8; c += nt) build1_chunk(dist, rm1, M, c);
    grid.sync();
    for (int t = bid; t < 8192; t += nb) tile_transpose(M, MT, tile, t, tid);
    grid.sync();

    // -------- loss1 Sinkhorn --------
    for (int it = 0; it < 50; ++it) {
        // A: wcol[r] = INV8192 / (MT[r] . wrow)
        stage_w(wrow, wl4, NR, tid);
        for (int r = wave; r < NC; r += 2 * nw) {
            int r2 = r + nw;
            float s0, s1;
            rowdot2_lds(MT + (size_t)r * NR, MT + (size_t)(r2 < NC ? r2 : r) * NR,
                        wl4, lane, s0, s1);
            if (lane == 0) {
                __hip_atomic_store(&wcol[r], __fdividef(INV8192, s0), __ATOMIC_RELAXED, AGENT);
                if (r2 < NC)
                    __hip_atomic_store(&wcol[r2], __fdividef(INV8192, s1), __ATOMIC_RELAXED, AGENT);
            }
        }
        gbar(ctr, ++pc * (unsigned)nb);
        if (it == 49) break;                   // last wrow update is dead
        // B: wrow[i] = INV4096 / (M[i] . wcol)
        stage_w(wcol, wl4, NC, tid);
        for (int r = wave; r < NR; r += nw) {
            float s = rowdot_lds<NC>(M + (size_t)r * NC, wl4, lane);
            if (lane == 0)
                __hip_atomic_store(&wrow[r], __fdividef(INV4096, s), __ATOMIC_RELAXED, AGENT);
        }
        gbar(ctr, ++pc * (unsigned)nb);
    }

    // -------- epi1 --------
    stage_w(wcol, wl4, NC, tid);
    for (int i = wave; i < NR; i += nw) epi1_row_lds(M, dist, wl4, rm1, arg1, out, i, lane);
    gbar(ctr, ++pc * (unsigned)nb);            // all M readers done before overwrite

    // -------- build M2 (= K2^T) + loss2 init --------
    for (int t = gt; t < NC; t += nt) {
        __hip_atomic_store(&wcol[t], INV8192, __ATOMIC_RELAXED, AGENT);
        __hip_atomic_store(&numb[t], 0.0f, __ATOMIC_RELAXED, AGENT);
        __hip_atomic_store(&denb[t], 0.0f, __ATOMIC_RELAXED, AGENT);
    }
    for (int c = gt; c < NR * NC / 8; c += nt) build2_chunk(dist, d12, M, c);
    grid.sync();
    for (int t = bid; t < 8192; t += nb) tile_transpose(M, MT, tile, t, tid);
    grid.sync();

    // -------- loss2 Sinkhorn --------
    for (int it = 0; it < 50; ++it) {
        // B2: wrow[r] = INV4096 / (M[r] . wcol)   (v update)
        stage_w(wcol, wl4, NC, tid);
        for (int r = wave; r < NR; r += nw) {
            float s = rowdot_lds<NC>(M + (size_t)r * NC, wl4, lane);
            if (lane == 0)
                __hip_atomic_store(&wrow[r], __fdividef(INV4096, s), __ATOMIC_RELAXED, AGENT);
        }
        gbar(ctr, ++pc * (unsigned)nb);
        if (it == 49) break;                   // last wcol update is dead
        // A2: wcol[r] = INV8192 / (MT[r] . wrow)  (u update)
        stage_w(wrow, wl4, NR, tid);
        for (int r = wave; r < NC; r += 2 * nw) {
            int r2 = r + nw;
            float s0, s1;
            rowdot2_lds(MT + (size_t)r * NR, MT + (size_t)(r2 < NC ? r2 : r) * NR,
                        wl4, lane, s0, s1);
            if (lane == 0) {
                __hip_atomic_store(&wcol[r], __fdividef(INV8192, s0), __ATOMIC_RELAXED, AGENT);
                if (r2 < NC)
                    __hip_atomic_store(&wcol[r2], __fdividef(INV8192, s1), __ATOMIC_RELAXED, AGENT);
            }
        }
        gbar(ctr, ++pc * (unsigned)nb);
    }

    // -------- epi2 --------
    for (int t = bid; t < 512; t += nb)
        epi2_body(M, dist, wrow, d12, numb, denb, wsm, t, tid, true);
    gbar(ctr, ++pc * (unsigned)nb);
    for (int t = wave; t < 128; t += nw) {
        int c = t * 64 + lane;
        float n = __hip_atomic_load(&numb[c], __ATOMIC_RELAXED, AGENT);
        float d = __hip_atomic_load(&denb[c], __ATOMIC_RELAXED, AGENT);
        float v = n / d;
#pragma unroll
        for (int o = 32; o; o >>= 1) v += __shfl_down(v, o);
        if (lane == 0) atomicAdd(out, v);
    }
}

// ------------------------- fallback multi-kernel path ----------------------
template <int W>
__device__ __forceinline__ float rowdot_g(const unsigned short* __restrict__ row,
                                          const float* __restrict__ w, int lane) {
    float acc = 0.0f;
#pragma unroll
    for (int s = 0; s < W; s += 512) {
        int j = s + lane * 8;
        uint4 a = *(const uint4*)(row + j);
        float4 w0 = *(const float4*)(w + j);
        float4 w1 = *(const float4*)(w + j + 4);
        acc = fmaf(bflo(a.x), w0.x, acc);
        acc = fmaf(bfhi(a.x), w0.y, acc);
        acc = fmaf(bflo(a.y), w0.z, acc);
        acc = fmaf(bfhi(a.y), w0.w, acc);
        acc = fmaf(bflo(a.z), w1.x, acc);
        acc = fmaf(bfhi(a.z), w1.y, acc);
        acc = fmaf(bflo(a.w), w1.z, acc);
        acc = fmaf(bfhi(a.w), w1.w, acc);
    }
#pragma unroll
    for (int o = 32; o; o >>= 1) acc += __shfl_down(acc, o);
    return acc;
}
__global__ __launch_bounds__(BLK) void k_fb_init(const float* __restrict__ dist,
                                                 float* __restrict__ rm1, int* __restrict__ arg1,
                                                 float* __restrict__ d12, float* __restrict__ wrow,
                                                 float* __restrict__ out) {
    init_body(dist, rm1, arg1, d12, wrow, out, blockIdx.x * BLK + threadIdx.x);
}
__global__ __launch_bounds__(BLK) void k_fb_build1(const float* __restrict__ dist,
                                                   const float* __restrict__ rm1,
                                                   unsigned short* __restrict__ M) {
    build1_chunk(dist, rm1, M, blockIdx.x * BLK + threadIdx.x);
}
__global__ __launch_bounds__(BLK) void k_fb_build2(const float* __restrict__ dist,
                                                   const float* __restrict__ d12,
                                                   unsigned short* __restrict__ M) {
    build2_chunk(dist, d12, M, blockIdx.x * BLK + threadIdx.x);
}
__global__ __launch_bounds__(BLK) void k_fb_transp(const unsigned short* __restrict__ M,
                                                   unsigned short* __restrict__ MT) {
    __shared__ unsigned int tile[64][33];
    tile_transpose(M, MT, tile, blockIdx.x, threadIdx.x);
}
template <int W>
__global__ __launch_bounds__(BLK) void k_fb_matvec(const unsigned short* __restrict__ Mat,
                                                   const float* __restrict__ w,
                                                   float* __restrict__ outv, float scale) {
    int r = blockIdx.x * 4 + (threadIdx.x >> 6);
    float s = rowdot_g<W>(Mat + (size_t)r * W, w, threadIdx.x & 63);
    if ((threadIdx.x & 63) == 0) outv[r] = __fdividef(scale, s);
}
__global__ __launch_bounds__(BLK) void k_fb_epi1(const unsigned short* __restrict__ M,
                                                 const float* __restrict__ dist,
                                                 const float* __restrict__ wcol,
                                                 const float* __restrict__ rm1,
                                                 const int* __restrict__ arg1,
                                                 float* __restrict__ out) {
    int i = blockIdx.x * 4 + (threadIdx.x >> 6);
    int lane = threadIdx.x & 63;
    float rm = rm1[i];
    int arg = arg1[i];
    const unsigned short* Ar = M + (size_t)i * NC;
    const float* Dr = dist + (size_t)i * DC + OFF;
    float num = 0.0f, den = 0.0f;
#pragma unroll 4
    for (int s = 0; s < NC; s += 512) {
        int j0 = s + lane * 8;
        uint4 a = *(const uint4*)(Ar + j0);
        float4 t0 = *(const float4*)(wcol + j0);
        float4 t1 = *(const float4*)(wcol + j0 + 4);
        float4 d0 = *(const float4*)(Dr + j0);
        float4 d1 = *(const float4*)(Dr + j0 + 4);
        float av[8] = {bflo(a.x), bfhi(a.x), bflo(a.y), bfhi(a.y),
                       bflo(a.z), bfhi(a.z), bflo(a.w), bfhi(a.w)};
        float tv[8] = {t0.x, t0.y, t0.z, t0.w, t1.x, t1.y, t1.z, t1.w};
        float dv[8] = {d0.x, d0.y, d0.z, d0.w, d1.x, d1.y, d1.z, d1.w};
#pragma unroll
        for (int e = 0; e < 8; ++e) {
            int jj = j0 + e;
            bool isdiag = (jj == i) || (jj == i + 4096);
            float gm = isdiag ? fmaxf(rm - 0.5f - dv[e], 0.0f)
                              : fmaxf(0.05f + dv[e] - rm, 0.0f);
            bool keep = (jj != arg) && ((jj < 4096) || (jj == i + 4096));
            float wv = keep ? av[e] * tv[e] : 0.0f;
            num += wv * gm;
            den += wv;
        }
    }
#pragma unroll
    for (int o = 32; o; o >>= 1) {
        num += __shfl_down(num, o);
        den += __shfl_down(den, o);
    }
    if (lane == 0) atomicAdd(out, num / den);
}
__global__ __launch_bounds__(BLK) void k_fb_init2(float* __restrict__ wcol,
                                                  float* __restrict__ numb,
                                                  float* __restrict__ denb) {
    int t = blockIdx.x * BLK + threadIdx.x;
    wcol[t] = INV8192;
    numb[t] = 0.0f;
    denb[t] = 0.0f;
}
__global__ __launch_bounds__(BLK) void k_fb_epi2(const unsigned short* __restrict__ M,
                                                 const float* __restrict__ dist,
                                                 const float* __restrict__ wrow,
                                                 const float* __restrict__ d12,
                                                 float* __restrict__ numb,
                                                 float* __restrict__ denb) {
    __shared__ float wsm[64];
    epi2_body(M, dist, wrow, d12, numb, denb, wsm, blockIdx.x, threadIdx.x, false);
}
__global__ __launch_bounds__(BLK) void k_fb_epi2fin(const float* __restrict__ numb,
                                                    const float* __restrict__ denb,
                                                    float* __restrict__ out) {
    int c = blockIdx.x * BLK + threadIdx.x;
    float v = numb[c] / denb[c];
    __shared__ float sm[4];
#pragma unroll
    for (int o = 32; o; o >>= 1) v += __shfl_down(v, o);
    if ((threadIdx.x & 63) == 0) sm[threadIdx.x >> 6] = v;
    __syncthreads();
    if (threadIdx.x == 0) atomicAdd(out, sm[0] + sm[1] + sm[2] + sm[3]);
}

// ---------------------------------------------------------------------------
extern "C" void kernel_launch(void* const* d_in, const int* in_sizes, int n_in,
                              void* d_out, int out_size, void* d_ws, size_t ws_size,
                              hipStream_t stream) {
    const float* dist = (const float*)d_in[0];
    float* out = (float*)d_out;

    unsigned short* M  = (unsigned short*)d_ws;                 // 64 MB
    unsigned short* MT = M + (size_t)NR * NC;                   // 64 MB
    float* fb   = (float*)(MT + (size_t)NR * NC);
    float* wrow = fb;                 // 4096
    float* wcol = wrow + NR;          // 8192
    float* rm1  = wcol + NC;          // 4096
    int*   arg1 = (int*)(rm1 + NR);   // 4096
    float* d12  = (float*)(arg1 + NR);// 8192
    float* numb = d12 + NC;           // 8192
    float* denb = numb + NC;          // 8192
    unsigned int* ctr = (unsigned int*)(denb + NC);

    // ---- cooperative persistent kernel with adaptive grid ----
    int dev = 0;
    (void)hipGetDevice(&dev);
    int numCU = 0;
    (void)hipDeviceGetAttribute(&numCU, hipDeviceAttributeMultiprocessorCount, dev);
    int maxPerCU = 0;
    (void)hipOccupancyMaxActiveBlocksPerMultiprocessor(&maxPerCU, (const void*)k_main,
                                                       BLK, 32768);
    hipError_t rc = hipErrorUnknown;
    int grid = (numCU > 0 && maxPerCU > 0) ? maxPerCU * numCU : 0;
    if (grid > 1024) grid = 1024;
    if (grid > 0) {
        (void)hipMemsetAsync(ctr, 0, sizeof(unsigned int), stream);  // barrier counter
        void* args[] = {(void*)&dist, (void*)&out, (void*)&M, (void*)&MT,
                        (void*)&wrow, (void*)&wcol, (void*)&rm1, (void*)&arg1,
                        (void*)&d12, (void*)&numb, (void*)&denb, (void*)&ctr};
        for (int g = grid; g >= 128 && rc != hipSuccess; g >>= 1) {
            rc = hipLaunchCooperativeKernel((void*)k_main, dim3(g), dim3(BLK),
                                            args, 32768, stream);
            if (rc != hipSuccess) (void)hipGetLastError();   // clear sticky error
        }
    }
    if (rc == hipSuccess) return;

    // ---- fallback: multi-kernel graph path (guaranteed) ----
    k_fb_init<<<32, BLK, 0, stream>>>(dist, rm1, arg1, d12, wrow, out);
    k_fb_build1<<<16384, BLK, 0, stream>>>(dist, rm1, M);
    k_fb_transp<<<8192, BLK, 0, stream>>>(M, MT);
    for (int it = 0; it < 50; ++it) {
        k_fb_matvec<NR><<<2048, BLK, 0, stream>>>(MT, wrow, wcol, INV8192);
        if (it == 49) break;
        k_fb_matvec<NC><<<1024, BLK, 0, stream>>>(M, wcol, wrow, INV4096);
    }
    k_fb_epi1<<<1024, BLK, 0, stream>>>(M, dist, wcol, rm1, arg1, out);

    k_fb_build2<<<16384, BLK, 0, stream>>>(dist, d12, M);
    k_fb_init2<<<32, BLK, 0, stream>>>(wcol, numb, denb);
    k_fb_transp<<<8192, BLK, 0, stream>>>(M, MT);
    for (int it = 0; it < 50; ++it) {
        k_fb_matvec<NC><<<1024, BLK, 0, stream>>>(M, wcol, wrow, INV4096);
        if (it == 49) break;
        k_fb_matvec<NR><<<2048, BLK, 0, stream>>>(MT, wrow, wcol, INV8192);
    }
    k_fb_epi2<<<512, BLK, 0, stream>>>(M, dist, wrow, d12, numb, denb);
    k_fb_epi2fin<<<32, BLK, 0, stream>>>(numb, denb, out);
}

// Round 6
// 3538.811 us; speedup vs baseline: 3.7484x; 1.8835x over previous
//
#include <hip/hip_runtime.h>
#include <hip/hip_cooperative_groups.h>
#include <math.h>

namespace cg = cooperative_groups;

#define DC 8220      // dist row stride (28 + 8192)
#define OFF 28
#define NR 4096      // rows of M
#define NC 8192      // cols of M
#define INV4096 (1.0f / 4096.0f)
#define INV8192 (1.0f / 8192.0f)
#define BLK 256

#define AGENT __HIP_MEMORY_SCOPE_AGENT

__device__ __forceinline__ float bflo(unsigned int u) { return __uint_as_float(u << 16); }
__device__ __forceinline__ float bfhi(unsigned int u) { return __uint_as_float(u & 0xffff0000u); }
__device__ __forceinline__ unsigned short f2bf(float f) {
    unsigned int i = __float_as_uint(f);
    return (unsigned short)((i + 0x7fffu + ((i >> 16) & 1u)) >> 16);   // RNE
}
// LDS bank swizzle on 16B granules
__device__ __forceinline__ int swz(int g) { return g ^ ((g >> 3) & 7); }

// --------------- tree grid barrier (no cache flush, spread counters) -------
// Arrivals spread over 64 counters 64B apart (<= nb/64 RMWs serialize per
// line). Block 0 wave 0 polls all 64 (one lane each), then publishes one
// release word; all blocks spin-read it (read-only). All cross-phase data
// moves via agent-scope atomics, so no L2 flush is needed.
__device__ __forceinline__ void gbar(unsigned int* ctrs, unsigned int* rel,
                                     unsigned int phase, int bid, int cpl) {
    __syncthreads();
    if (threadIdx.x == 0) {
        asm volatile("s_waitcnt vmcnt(0)" ::: "memory");   // drain prior stores
        __hip_atomic_fetch_add(&ctrs[(bid & 63) * 16], 1u, __ATOMIC_RELAXED, AGENT);
    }
    if (bid == 0) {
        if (threadIdx.x < 64) {
            unsigned int tgt = phase * (unsigned int)cpl;
            while (__hip_atomic_load(&ctrs[threadIdx.x * 16], __ATOMIC_RELAXED, AGENT) < tgt)
                __builtin_amdgcn_s_sleep(2);
        }
        __syncthreads();
        if (threadIdx.x == 0)
            __hip_atomic_store(rel, phase, __ATOMIC_RELAXED, AGENT);
    }
    if (threadIdx.x == 0) {
        while (__hip_atomic_load(rel, __ATOMIC_RELAXED, AGENT) < phase)
            __builtin_amdgcn_s_sleep(2);
    }
    __syncthreads();
}

// stage n floats of w (atomic, coherent) into swizzled LDS granules
__device__ __forceinline__ void stage_w(const float* __restrict__ w, float4* wl4,
                                        int n, int tid) {
    for (int g = tid; g < (n >> 2); g += BLK) {
        unsigned long long lo = __hip_atomic_load((unsigned long long*)(w + g * 4),
                                                  __ATOMIC_RELAXED, AGENT);
        unsigned long long hi = __hip_atomic_load((unsigned long long*)(w + g * 4 + 2),
                                                  __ATOMIC_RELAXED, AGENT);
        float4 v;
        v.x = __uint_as_float((unsigned int)lo);
        v.y = __uint_as_float((unsigned int)(lo >> 32));
        v.z = __uint_as_float((unsigned int)hi);
        v.w = __uint_as_float((unsigned int)(hi >> 32));
        wl4[swz(g)] = v;
    }
    __syncthreads();
}

// rowdot: one row, w from swizzled LDS
template <int W>
__device__ __forceinline__ float rowdot_lds(const unsigned short* __restrict__ row,
                                            const float4* __restrict__ wl4, int lane) {
    float acc = 0.0f;
#pragma unroll 8
    for (int s = 0; s < W; s += 512) {
        int j = s + lane * 8;
        uint4 a = *(const uint4*)(row + j);
        int g = j >> 2;
        float4 w0 = wl4[swz(g)];
        float4 w1 = wl4[swz(g + 1)];
        acc = fmaf(bflo(a.x), w0.x, acc);
        acc = fmaf(bfhi(a.x), w0.y, acc);
        acc = fmaf(bflo(a.y), w0.z, acc);
        acc = fmaf(bfhi(a.y), w0.w, acc);
        acc = fmaf(bflo(a.z), w1.x, acc);
        acc = fmaf(bfhi(a.z), w1.y, acc);
        acc = fmaf(bflo(a.w), w1.z, acc);
        acc = fmaf(bfhi(a.w), w1.w, acc);
    }
#pragma unroll
    for (int o = 32; o; o >>= 1) acc += __shfl_down(acc, o);
    return acc;
}

// rowdot for two rows sharing one w
__device__ __forceinline__ void rowdot2_lds(const unsigned short* __restrict__ r0,
                                            const unsigned short* __restrict__ r1,
                                            const float4* __restrict__ wl4, int lane,
                                            float& o0, float& o1) {
    float a0 = 0.0f, a1 = 0.0f;
#pragma unroll
    for (int s = 0; s < NR; s += 512) {
        int j = s + lane * 8;
        uint4 a = *(const uint4*)(r0 + j);
        uint4 b = *(const uint4*)(r1 + j);
        int g = j >> 2;
        float4 w0 = wl4[swz(g)];
        float4 w1 = wl4[swz(g + 1)];
        a0 = fmaf(bflo(a.x), w0.x, a0); a1 = fmaf(bflo(b.x), w0.x, a1);
        a0 = fmaf(bfhi(a.x), w0.y, a0); a1 = fmaf(bfhi(b.x), w0.y, a1);
        a0 = fmaf(bflo(a.y), w0.z, a0); a1 = fmaf(bflo(b.y), w0.z, a1);
        a0 = fmaf(bfhi(a.y), w0.w, a0); a1 = fmaf(bfhi(b.y), w0.w, a1);
        a0 = fmaf(bflo(a.z), w1.x, a0); a1 = fmaf(bflo(b.z), w1.x, a1);
        a0 = fmaf(bfhi(a.z), w1.y, a0); a1 = fmaf(bfhi(b.z), w1.y, a1);
        a0 = fmaf(bflo(a.w), w1.z, a0); a1 = fmaf(bflo(b.w), w1.z, a1);
        a0 = fmaf(bfhi(a.w), w1.w, a0); a1 = fmaf(bfhi(b.w), w1.w, a1);
    }
#pragma unroll
    for (int o = 32; o; o >>= 1) {
        a0 += __shfl_down(a0, o);
        a1 += __shfl_down(a1, o);
    }
    o0 = a0; o1 = a1;
}

// ---------------- shared phase bodies (also used by fallback) --------------
__device__ __forceinline__ void init_body(const float* __restrict__ dist,
                                          float* __restrict__ rm1, int* __restrict__ arg1,
                                          float* __restrict__ d12, float* __restrict__ wrow,
                                          float* __restrict__ out, int t) {
    if (t == 0) __hip_atomic_store(out, 0.0f, __ATOMIC_RELAXED, AGENT);
    if (t < NR) {
        float a = dist[(size_t)t * DC + OFF + t];
        float b = dist[(size_t)t * DC + OFF + 4096 + t];
        rm1[t] = fmaxf(a, b);
        arg1[t] = (a >= b) ? t : t + 4096;     // jnp.argmax: first max wins
        __hip_atomic_store(&wrow[t], INV4096, __ATOMIC_RELAXED, AGENT);
    }
    d12[t] = dist[(size_t)(t & 4095) * DC + OFF + t];
}

__device__ __forceinline__ void build1_chunk(const float* __restrict__ dist,
                                             const float* __restrict__ rm1,
                                             unsigned short* __restrict__ M, int c) {
    int i = c >> 10;
    int j = (c & 1023) << 3;
    float rm = rm1[i];
    const float* Dr = dist + (size_t)i * DC + OFF + j;
    float4 d0 = *(const float4*)Dr;
    float4 d1 = *(const float4*)(Dr + 4);
    float dv[8] = {d0.x, d0.y, d0.z, d0.w, d1.x, d1.y, d1.z, d1.w};
    unsigned short e[8];
#pragma unroll
    for (int k = 0; k < 8; ++k) {
        int jj = j + k;
        bool diag = (jj == i) || (jj == i + 4096);
        float gm = diag ? 0.0f : fmaxf(0.05f + dv[k] - rm, 0.0f);
        e[k] = f2bf(__expf(5.0f * __expf(-gm)));
    }
    uint4 o;
    o.x = (unsigned int)e[0] | ((unsigned int)e[1] << 16);
    o.y = (unsigned int)e[2] | ((unsigned int)e[3] << 16);
    o.z = (unsigned int)e[4] | ((unsigned int)e[5] << 16);
    o.w = (unsigned int)e[6] | ((unsigned int)e[7] << 16);
    *(uint4*)(M + (size_t)c * 8) = o;
}

__device__ __forceinline__ void build2_chunk(const float* __restrict__ dist,
                                             const float* __restrict__ d12,
                                             unsigned short* __restrict__ M, int c) {
    int r = c >> 10;
    int col = (c & 1023) << 3;
    const float* Dr = dist + (size_t)r * DC + OFF + col;
    float4 d0 = *(const float4*)Dr;
    float4 d1 = *(const float4*)(Dr + 4);
    float4 e0 = *(const float4*)(d12 + col);
    float4 e1 = *(const float4*)(d12 + col + 4);
    float dv[8] = {d0.x, d0.y, d0.z, d0.w, d1.x, d1.y, d1.z, d1.w};
    float dd[8] = {e0.x, e0.y, e0.z, e0.w, e1.x, e1.y, e1.z, e1.w};
    unsigned short e[8];
#pragma unroll
    for (int k = 0; k < 8; ++k) {
        int cc = col + k;
        bool diag = (r == (cc & 4095));
        float gm = diag ? 0.0f : fmaxf(0.05f + dv[k] - dd[k], 0.0f);
        e[k] = f2bf(__expf(5.0f * __expf(-gm)));
    }
    uint4 o;
    o.x = (unsigned int)e[0] | ((unsigned int)e[1] << 16);
    o.y = (unsigned int)e[2] | ((unsigned int)e[3] << 16);
    o.z = (unsigned int)e[4] | ((unsigned int)e[5] << 16);
    o.w = (unsigned int)e[6] | ((unsigned int)e[7] << 16);
    *(uint4*)(M + (size_t)c * 8) = o;
}

__device__ __forceinline__ void tile_transpose(const unsigned short* __restrict__ M,
                                               unsigned short* __restrict__ MT,
                                               unsigned int (*tile)[33], int t, int tid) {
    int r0 = (t >> 7) * 64;
    int c0 = (t & 127) * 64;
    int lc = tid & 7, rr = tid >> 3;
#pragma unroll
    for (int s = 0; s < 2; ++s) {
        int r = rr + s * 32;
        uint4 a = *(const uint4*)(M + (size_t)(r0 + r) * NC + c0 + lc * 8);
        tile[r][lc * 4 + 0] = a.x;
        tile[r][lc * 4 + 1] = a.y;
        tile[r][lc * 4 + 2] = a.z;
        tile[r][lc * 4 + 3] = a.w;
    }
    __syncthreads();
    int cc = tid >> 2, rs = (tid & 3) * 16;
    unsigned int o[8];
#pragma unroll
    for (int w = 0; w < 8; ++w) {
        unsigned int ue = tile[rs + 2 * w][cc >> 1];
        unsigned int uo = tile[rs + 2 * w + 1][cc >> 1];
        unsigned short e = (cc & 1) ? (unsigned short)(ue >> 16) : (unsigned short)(ue & 0xffffu);
        unsigned short d = (cc & 1) ? (unsigned short)(uo >> 16) : (unsigned short)(uo & 0xffffu);
        o[w] = (unsigned int)e | ((unsigned int)d << 16);
    }
    unsigned short* dst = MT + (size_t)(c0 + cc) * NR + r0 + rs;
    *(uint4*)dst = make_uint4(o[0], o[1], o[2], o[3]);
    *(uint4*)(dst + 8) = make_uint4(o[4], o[5], o[6], o[7]);
    __syncthreads();
}

__device__ __forceinline__ void epi1_row_lds(const unsigned short* __restrict__ M,
                                             const float* __restrict__ dist,
                                             const float4* __restrict__ wl4,
                                             const float* __restrict__ rm1,
                                             const int* __restrict__ arg1,
                                             float* __restrict__ out, int i, int lane) {
    float rm = rm1[i];
    int arg = arg1[i];
    const unsigned short* Ar = M + (size_t)i * NC;
    const float* Dr = dist + (size_t)i * DC + OFF;
    float num = 0.0f, den = 0.0f;
#pragma unroll 4
    for (int s = 0; s < NC; s += 512) {
        int j0 = s + lane * 8;
        uint4 a = *(const uint4*)(Ar + j0);
        int g = j0 >> 2;
        float4 t0 = wl4[swz(g)];
        float4 t1 = wl4[swz(g + 1)];
        float4 d0 = *(const float4*)(Dr + j0);
        float4 d1 = *(const float4*)(Dr + j0 + 4);
        float av[8] = {bflo(a.x), bfhi(a.x), bflo(a.y), bfhi(a.y),
                       bflo(a.z), bfhi(a.z), bflo(a.w), bfhi(a.w)};
        float tv[8] = {t0.x, t0.y, t0.z, t0.w, t1.x, t1.y, t1.z, t1.w};
        float dv[8] = {d0.x, d0.y, d0.z, d0.w, d1.x, d1.y, d1.z, d1.w};
#pragma unroll
        for (int e = 0; e < 8; ++e) {
            int jj = j0 + e;
            bool isdiag = (jj == i) || (jj == i + 4096);
            float gm = isdiag ? fmaxf(rm - 0.5f - dv[e], 0.0f)
                              : fmaxf(0.05f + dv[e] - rm, 0.0f);
            bool keep = (jj != arg) && ((jj < 4096) || (jj == i + 4096));
            float wv = keep ? av[e] * tv[e] : 0.0f;
            num += wv * gm;
            den += wv;
        }
    }
#pragma unroll
    for (int o = 32; o; o >>= 1) {
        num += __shfl_down(num, o);
        den += __shfl_down(den, o);
    }
    if (lane == 0) atomicAdd(out, num / den);
}

__device__ __forceinline__ void epi2_body(const unsigned short* __restrict__ M,
                                          const float* __restrict__ dist,
                                          const float* __restrict__ wrow,
                                          const float* __restrict__ d12,
                                          float* __restrict__ numb, float* __restrict__ denb,
                                          float* wsm, int t, int tid, bool coherent_w) {
    int r0 = (t >> 3) * 64;
    int c = (t & 7) * 1024 + tid * 4;
    if (tid < 64) {
        wsm[tid] = coherent_w ? __hip_atomic_load(&wrow[r0 + tid], __ATOMIC_RELAXED, AGENT)
                              : wrow[r0 + tid];
    }
    __syncthreads();
    float4 e0 = *(const float4*)(d12 + c);
    float dd[4] = {e0.x, e0.y, e0.z, e0.w};
    float nacc[4] = {0.f, 0.f, 0.f, 0.f};
    float dacc[4] = {0.f, 0.f, 0.f, 0.f};
    for (int r = 0; r < 64; ++r) {
        int rr = r0 + r;
        uint2 a = *(const uint2*)(M + (size_t)rr * NC + c);
        float4 dv4 = *(const float4*)(dist + (size_t)rr * DC + OFF + c);
        float av[4] = {bflo(a.x), bfhi(a.x), bflo(a.y), bfhi(a.y)};
        float dv[4] = {dv4.x, dv4.y, dv4.z, dv4.w};
        float ww = wsm[r];
#pragma unroll
        for (int e = 0; e < 4; ++e) {
            int cc = c + e;
            bool isdiag = (rr == (cc & 4095));
            float gm = fmaxf(0.05f + dv[e] - dd[e], 0.0f);
            float wv = isdiag ? 0.0f : av[e] * ww;
            nacc[e] += wv * gm;
            dacc[e] += wv;
        }
    }
#pragma unroll
    for (int e = 0; e < 4; ++e) {
        atomicAdd(&numb[c + e], nacc[e]);
        atomicAdd(&denb[c + e], dacc[e]);
    }
    __syncthreads();
}

// ------------------------- cooperative persistent kernel -------------------
__global__ __launch_bounds__(BLK, 4) void k_main(const float* __restrict__ dist,
                                                 float* __restrict__ out,
                                                 unsigned short* __restrict__ M,
                                                 unsigned short* __restrict__ MT,
                                                 float* __restrict__ wrow,
                                                 float* __restrict__ wcol,
                                                 float* __restrict__ rm1,
                                                 int* __restrict__ arg1,
                                                 float* __restrict__ d12,
                                                 float* __restrict__ numb,
                                                 float* __restrict__ denb,
                                                 unsigned int* __restrict__ ctrs,
                                                 unsigned int* __restrict__ rel) {
    cg::grid_group grid = cg::this_grid();
    const int tid = threadIdx.x, bid = blockIdx.x;
    const int nb = gridDim.x, nt = nb * BLK;
    const int gt = bid * BLK + tid;
    const int nw = nt >> 6, wave = gt >> 6, lane = tid & 63;
    const int cpl = nb >> 6;                   // blocks per arrival counter
    unsigned int pc = 0;                       // barrier phase count

    extern __shared__ char smem[];             // 32 KB dynamic
    float4* wl4 = (float4*)smem;
    unsigned int (*tile)[33] = (unsigned int(*)[33])smem;
    float* wsm = (float*)smem;

    for (int t = gt; t < NC; t += nt) init_body(dist, rm1, arg1, d12, wrow, out, t);
    grid.sync();
    for (int c = gt; c < NR * NC / 8; c += nt) build1_chunk(dist, rm1, M, c);
    grid.sync();
    for (int t = bid; t < 8192; t += nb) tile_transpose(M, MT, tile, t, tid);
    grid.sync();

    // -------- loss1 Sinkhorn --------
    for (int it = 0; it < 50; ++it) {
        // A: wcol[r] = INV8192 / (MT[r] . wrow)
        stage_w(wrow, wl4, NR, tid);
        for (int r = wave; r < NC; r += 2 * nw) {
            int r2 = r + nw;
            float s0, s1;
            rowdot2_lds(MT + (size_t)r * NR, MT + (size_t)(r2 < NC ? r2 : r) * NR,
                        wl4, lane, s0, s1);
            if (lane == 0) {
                __hip_atomic_store(&wcol[r], __fdividef(INV8192, s0), __ATOMIC_RELAXED, AGENT);
                if (r2 < NC)
                    __hip_atomic_store(&wcol[r2], __fdividef(INV8192, s1), __ATOMIC_RELAXED, AGENT);
            }
        }
        gbar(ctrs, rel, ++pc, bid, cpl);
        if (it == 49) break;                   // last wrow update is dead
        // B: wrow[i] = INV4096 / (M[i] . wcol)
        stage_w(wcol, wl4, NC, tid);
        for (int r = wave; r < NR; r += nw) {
            float s = rowdot_lds<NC>(M + (size_t)r * NC, wl4, lane);
            if (lane == 0)
                __hip_atomic_store(&wrow[r], __fdividef(INV4096, s), __ATOMIC_RELAXED, AGENT);
        }
        gbar(ctrs, rel, ++pc, bid, cpl);
    }

    // -------- epi1 --------
    stage_w(wcol, wl4, NC, tid);
    for (int i = wave; i < NR; i += nw) epi1_row_lds(M, dist, wl4, rm1, arg1, out, i, lane);
    gbar(ctrs, rel, ++pc, bid, cpl);           // all M readers done before overwrite

    // -------- build M2 (= K2^T) + loss2 init --------
    for (int t = gt; t < NC; t += nt) {
        __hip_atomic_store(&wcol[t], INV8192, __ATOMIC_RELAXED, AGENT);
        __hip_atomic_store(&numb[t], 0.0f, __ATOMIC_RELAXED, AGENT);
        __hip_atomic_store(&denb[t], 0.0f, __ATOMIC_RELAXED, AGENT);
    }
    for (int c = gt; c < NR * NC / 8; c += nt) build2_chunk(dist, d12, M, c);
    grid.sync();
    for (int t = bid; t < 8192; t += nb) tile_transpose(M, MT, tile, t, tid);
    grid.sync();

    // -------- loss2 Sinkhorn --------
    for (int it = 0; it < 50; ++it) {
        // B2: wrow[r] = INV4096 / (M[r] . wcol)   (v update)
        stage_w(wcol, wl4, NC, tid);
        for (int r = wave; r < NR; r += nw) {
            float s = rowdot_lds<NC>(M + (size_t)r * NC, wl4, lane);
            if (lane == 0)
                __hip_atomic_store(&wrow[r], __fdividef(INV4096, s), __ATOMIC_RELAXED, AGENT);
        }
        gbar(ctrs, rel, ++pc, bid, cpl);
        if (it == 49) break;                   // last wcol update is dead
        // A2: wcol[r] = INV8192 / (MT[r] . wrow)  (u update)
        stage_w(wrow, wl4, NR, tid);
        for (int r = wave; r < NC; r += 2 * nw) {
            int r2 = r + nw;
            float s0, s1;
            rowdot2_lds(MT + (size_t)r * NR, MT + (size_t)(r2 < NC ? r2 : r) * NR,
                        wl4, lane, s0, s1);
            if (lane == 0) {
                __hip_atomic_store(&wcol[r], __fdividef(INV8192, s0), __ATOMIC_RELAXED, AGENT);
                if (r2 < NC)
                    __hip_atomic_store(&wcol[r2], __fdividef(INV8192, s1), __ATOMIC_RELAXED, AGENT);
            }
        }
        gbar(ctrs, rel, ++pc, bid, cpl);
    }

    // -------- epi2 --------
    for (int t = bid; t < 512; t += nb)
        epi2_body(M, dist, wrow, d12, numb, denb, wsm, t, tid, true);
    gbar(ctrs, rel, ++pc, bid, cpl);
    for (int t = wave; t < 128; t += nw) {
        int c = t * 64 + lane;
        float n = __hip_atomic_load(&numb[c], __ATOMIC_RELAXED, AGENT);
        float d = __hip_atomic_load(&denb[c], __ATOMIC_RELAXED, AGENT);
        float v = n / d;
#pragma unroll
        for (int o = 32; o; o >>= 1) v += __shfl_down(v, o);
        if (lane == 0) atomicAdd(out, v);
    }
}

// ------------------------- fallback multi-kernel path ----------------------
template <int W>
__device__ __forceinline__ float rowdot_g(const unsigned short* __restrict__ row,
                                          const float* __restrict__ w, int lane) {
    float acc = 0.0f;
#pragma unroll
    for (int s = 0; s < W; s += 512) {
        int j = s + lane * 8;
        uint4 a = *(const uint4*)(row + j);
        float4 w0 = *(const float4*)(w + j);
        float4 w1 = *(const float4*)(w + j + 4);
        acc = fmaf(bflo(a.x), w0.x, acc);
        acc = fmaf(bfhi(a.x), w0.y, acc);
        acc = fmaf(bflo(a.y), w0.z, acc);
        acc = fmaf(bfhi(a.y), w0.w, acc);
        acc = fmaf(bflo(a.z), w1.x, acc);
        acc = fmaf(bfhi(a.z), w1.y, acc);
        acc = fmaf(bflo(a.w), w1.z, acc);
        acc = fmaf(bfhi(a.w), w1.w, acc);
    }
#pragma unroll
    for (int o = 32; o; o >>= 1) acc += __shfl_down(acc, o);
    return acc;
}
__global__ __launch_bounds__(BLK) void k_fb_init(const float* __restrict__ dist,
                                                 float* __restrict__ rm1, int* __restrict__ arg1,
                                                 float* __restrict__ d12, float* __restrict__ wrow,
                                                 float* __restrict__ out) {
    init_body(dist, rm1, arg1, d12, wrow, out, blockIdx.x * BLK + threadIdx.x);
}
__global__ __launch_bounds__(BLK) void k_fb_build1(const float* __restrict__ dist,
                                                   const float* __restrict__ rm1,
                                                   unsigned short* __restrict__ M) {
    build1_chunk(dist, rm1, M, blockIdx.x * BLK + threadIdx.x);
}
__global__ __launch_bounds__(BLK) void k_fb_build2(const float* __restrict__ dist,
                                                   const float* __restrict__ d12,
                                                   unsigned short* __restrict__ M) {
    build2_chunk(dist, d12, M, blockIdx.x * BLK + threadIdx.x);
}
__global__ __launch_bounds__(BLK) void k_fb_transp(const unsigned short* __restrict__ M,
                                                   unsigned short* __restrict__ MT) {
    __shared__ unsigned int tile[64][33];
    tile_transpose(M, MT, tile, blockIdx.x, threadIdx.x);
}
template <int W>
__global__ __launch_bounds__(BLK) void k_fb_matvec(const unsigned short* __restrict__ Mat,
                                                   const float* __restrict__ w,
                                                   float* __restrict__ outv, float scale) {
    int r = blockIdx.x * 4 + (threadIdx.x >> 6);
    float s = rowdot_g<W>(Mat + (size_t)r * W, w, threadIdx.x & 63);
    if ((threadIdx.x & 63) == 0) outv[r] = __fdividef(scale, s);
}
__global__ __launch_bounds__(BLK) void k_fb_epi1(const unsigned short* __restrict__ M,
                                                 const float* __restrict__ dist,
                                                 const float* __restrict__ wcol,
                                                 const float* __restrict__ rm1,
                                                 const int* __restrict__ arg1,
                                                 float* __restrict__ out) {
    int i = blockIdx.x * 4 + (threadIdx.x >> 6);
    int lane = threadIdx.x & 63;
    float rm = rm1[i];
    int arg = arg1[i];
    const unsigned short* Ar = M + (size_t)i * NC;
    const float* Dr = dist + (size_t)i * DC + OFF;
    float num = 0.0f, den = 0.0f;
#pragma unroll 4
    for (int s = 0; s < NC; s += 512) {
        int j0 = s + lane * 8;
        uint4 a = *(const uint4*)(Ar + j0);
        float4 t0 = *(const float4*)(wcol + j0);
        float4 t1 = *(const float4*)(wcol + j0 + 4);
        float4 d0 = *(const float4*)(Dr + j0);
        float4 d1 = *(const float4*)(Dr + j0 + 4);
        float av[8] = {bflo(a.x), bfhi(a.x), bflo(a.y), bfhi(a.y),
                       bflo(a.z), bfhi(a.z), bflo(a.w), bfhi(a.w)};
        float tv[8] = {t0.x, t0.y, t0.z, t0.w, t1.x, t1.y, t1.z, t1.w};
        float dv[8] = {d0.x, d0.y, d0.z, d0.w, d1.x, d1.y, d1.z, d1.w};
#pragma unroll
        for (int e = 0; e < 8; ++e) {
            int jj = j0 + e;
            bool isdiag = (jj == i) || (jj == i + 4096);
            float gm = isdiag ? fmaxf(rm - 0.5f - dv[e], 0.0f)
                              : fmaxf(0.05f + dv[e] - rm, 0.0f);
            bool keep = (jj != arg) && ((jj < 4096) || (jj == i + 4096));
            float wv = keep ? av[e] * tv[e] : 0.0f;
            num += wv * gm;
            den += wv;
        }
    }
#pragma unroll
    for (int o = 32; o; o >>= 1) {
        num += __shfl_down(num, o);
        den += __shfl_down(den, o);
    }
    if (lane == 0) atomicAdd(out, num / den);
}
__global__ __launch_bounds__(BLK) void k_fb_init2(float* __restrict__ wcol,
                                                  float* __restrict__ numb,
                                                  float* __restrict__ denb) {
    int t = blockIdx.x * BLK + threadIdx.x;
    wcol[t] = INV8192;
    numb[t] = 0.0f;
    denb[t] = 0.0f;
}
__global__ __launch_bounds__(BLK) void k_fb_epi2(const unsigned short* __restrict__ M,
                                                 const float* __restrict__ dist,
                                                 const float* __restrict__ wrow,
                                                 const float* __restrict__ d12,
                                                 float* __restrict__ numb,
                                                 float* __restrict__ denb) {
    __shared__ float wsm[64];
    epi2_body(M, dist, wrow, d12, numb, denb, wsm, blockIdx.x, threadIdx.x, false);
}
__global__ __launch_bounds__(BLK) void k_fb_epi2fin(const float* __restrict__ numb,
                                                    const float* __restrict__ denb,
                                                    float* __restrict__ out) {
    int c = blockIdx.x * BLK + threadIdx.x;
    float v = numb[c] / denb[c];
    __shared__ float sm[4];
#pragma unroll
    for (int o = 32; o; o >>= 1) v += __shfl_down(v, o);
    if ((threadIdx.x & 63) == 0) sm[threadIdx.x >> 6] = v;
    __syncthreads();
    if (threadIdx.x == 0) atomicAdd(out, sm[0] + sm[1] + sm[2] + sm[3]);
}

// ---------------------------------------------------------------------------
extern "C" void kernel_launch(void* const* d_in, const int* in_sizes, int n_in,
                              void* d_out, int out_size, void* d_ws, size_t ws_size,
                              hipStream_t stream) {
    const float* dist = (const float*)d_in[0];
    float* out = (float*)d_out;

    unsigned short* M  = (unsigned short*)d_ws;                 // 64 MB
    unsigned short* MT = M + (size_t)NR * NC;                   // 64 MB
    float* fb   = (float*)(MT + (size_t)NR * NC);
    float* wrow = fb;                 // 4096
    float* wcol = wrow + NR;          // 8192
    float* rm1  = wcol + NC;          // 4096
    int*   arg1 = (int*)(rm1 + NR);   // 4096
    float* d12  = (float*)(arg1 + NR);// 8192
    float* numb = d12 + NC;           // 8192
    float* denb = numb + NC;          // 8192
    unsigned int* ctrs = (unsigned int*)(denb + NC);   // 64 counters * 16 u32
    unsigned int* rel  = ctrs + 64 * 16;               // release flag

    // ---- cooperative persistent kernel with adaptive grid ----
    int dev = 0;
    (void)hipGetDevice(&dev);
    int numCU = 0;
    (void)hipDeviceGetAttribute(&numCU, hipDeviceAttributeMultiprocessorCount, dev);
    int maxPerCU = 0;
    (void)hipOccupancyMaxActiveBlocksPerMultiprocessor(&maxPerCU, (const void*)k_main,
                                                       BLK, 32768);
    hipError_t rc = hipErrorUnknown;
    int grid = (numCU > 0 && maxPerCU > 0) ? maxPerCU * numCU : 0;
    if (grid > 2048) grid = 2048;
    grid &= ~63;                                   // multiple of 64 (cpl exact)
    if (grid > 0) {
        (void)hipMemsetAsync(ctrs, 0, (64 * 16 + 16) * sizeof(unsigned int), stream);
        void* args[] = {(void*)&dist, (void*)&out, (void*)&M, (void*)&MT,
                        (void*)&wrow, (void*)&wcol, (void*)&rm1, (void*)&arg1,
                        (void*)&d12, (void*)&numb, (void*)&denb,
                        (void*)&ctrs, (void*)&rel};
        for (int g = grid; g >= 128 && rc != hipSuccess; g = (g / 2) & ~63) {
            rc = hipLaunchCooperativeKernel((void*)k_main, dim3(g), dim3(BLK),
                                            args, 32768, stream);
            if (rc != hipSuccess) (void)hipGetLastError();   // clear sticky error
        }
    }
    if (rc == hipSuccess) return;

    // ---- fallback: multi-kernel graph path (guaranteed) ----
    k_fb_init<<<32, BLK, 0, stream>>>(dist, rm1, arg1, d12, wrow, out);
    k_fb_build1<<<16384, BLK, 0, stream>>>(dist, rm1, M);
    k_fb_transp<<<8192, BLK, 0, stream>>>(M, MT);
    for (int it = 0; it < 50; ++it) {
        k_fb_matvec<NR><<<2048, BLK, 0, stream>>>(MT, wrow, wcol, INV8192);
        if (it == 49) break;
        k_fb_matvec<NC><<<1024, BLK, 0, stream>>>(M, wcol, wrow, INV4096);
    }
    k_fb_epi1<<<1024, BLK, 0, stream>>>(M, dist, wcol, rm1, arg1, out);

    k_fb_build2<<<16384, BLK, 0, stream>>>(dist, d12, M);
    k_fb_init2<<<32, BLK, 0, stream>>>(wcol, numb, denb);
    k_fb_transp<<<8192, BLK, 0, stream>>>(M, MT);
    for (int it = 0; it < 50; ++it) {
        k_fb_matvec<NC><<<1024, BLK, 0, stream>>>(M, wcol, wrow, INV4096);
        if (it == 49) break;
        k_fb_matvec<NR><<<2048, BLK, 0, stream>>>(MT, wrow, wcol, INV8192);
    }
    k_fb_epi2<<<512, BLK, 0, stream>>>(M, dist, wrow, d12, numb, denb);
    k_fb_epi2fin<<<32, BLK, 0, stream>>>(numb, denb, out);
}